// Round 15
// baseline (42.900 us; speedup 1.0000x reference)
//
#include <hip/hip_runtime.h>

// Window_Crop: sliding-window avgpool over 5 aspect ratios + argmax (grps 0-3).
//
// Ratios (exact Python float semantics: 1024 // 25.6 == 39.0):
//   g0 (32,32) off 0      g1 (25,39) off 6561   g2 (39,25) off 13073
//   g3 (38,26) off 19585  g4 (26,38) off 26110 (not in argmax)  total 32635
//
// R15: crew-balanced wave specialization (fixes R13's imbalance+occupancy
// bugs). grid=256 = 1 block/CU, 1024 thr = 16 waves (same as R7). Waves 0-11
// = window crew: compute+store scores for image n -- the HBM write stream
// never stops. Waves 12-15 (256 thr) = prep crew: load image n+1 + rowscan +
// colscan, ordered by an LDS-atomic spin sync among the 4 prep waves (window
// crew never joins these sub-syncs). One LDS-only block barrier per image.
// Double-buffered 113x113 integrals (102 KB dynamic LDS).

#define B_TOTAL 1024
#define GRID    256
#define IMGS    4
#define HW      112
#define NPIX    (HW * HW)
#define NV4     (NPIX / 4)           // 3136 float4 per image
#define PITCH   113
#define ISZ     (PITCH * PITCH)      // 12769 floats = 51,076 B per buffer
#define TOTAL_W 32635
#define BLOCK   1024
#define WCREW   768                  // window crew threads (12 waves)
#define PCREW   256                  // prep crew threads (4 waves)
#define SEG     28

// LDS-only barrier: drains LDS ops, NOT the global store queue (R14-validated)
#define BAR() asm volatile("s_waitcnt lgkmcnt(0)\n\ts_barrier" ::: "memory")

__shared__ int pctr;                 // prep-crew phase counter

__device__ __forceinline__ void psync(int lane, int target) {
    asm volatile("s_waitcnt lgkmcnt(0)" ::: "memory");   // own LDS writes done
    if (lane == 0) atomicAdd(&pctr, 1);
    while (*(volatile int*)&pctr < target) __builtin_amdgcn_s_sleep(2);
    asm volatile("" ::: "memory");
}

template<int KH, int KW, int OFF, bool TRACK>
__device__ __forceinline__ void windows_group(const float* __restrict__ S,
                                              float* __restrict__ gout,
                                              int t, float& bv, int& bi) {
    constexpr int OH = HW - KH + 1;
    constexpr int OW = HW - KW + 1;
    constexpr int N  = OH * OW;
    constexpr int D  = KH * PITCH;
    constexpr float inv = 1.0f / (float)(KH * KW);
    for (int w = t; w < N; w += WCREW) {
        const int i  = w / OW;            // const divisor -> magic mul
        const int j  = w - i * OW;
        const int A  = i * PITCH + j;
        const int Ab = A + D;
        const float sc = (S[Ab + KW] - S[A + KW] - S[Ab] + S[A]) * inv;
        gout[OFF + w] = sc;               // stride-1 lanes: packed 256B/wave
        if (TRACK && sc > bv) { bv = sc; bi = OFF + w; }
    }
}

__device__ __forceinline__ void load_img(const float* __restrict__ x, int b,
                                         float* __restrict__ S, int t0, int nt) {
    const float4* img = (const float4*)(x + (size_t)b * NPIX);
    for (int i = t0; i < NV4; i += nt) {
        const int r = i / 28;             // 28 float4 per image row
        const int c = (i - r * 28) * 4;
        const float4 v = img[i];
        float* dst = &S[(r + 1) * PITCH + c + 1];
        dst[0] = v.x; dst[1] = v.y; dst[2] = v.z; dst[3] = v.w;
    }
}

// 448 row-scan tasks (112 rows x 4 segs of 28); tasks 4r..4r+3 land on one
// 4-lane shfl group in every stride-(multiple of 4) round.
__device__ __forceinline__ void rowscan_t(float* __restrict__ S, int t0, int nt,
                                          int lane) {
    const int bl = lane & ~3;
    for (int t = t0; t < HW * 4; t += nt) {
        const int r = t >> 2, s = t & 3;
        float* row = &S[(r + 1) * PITCH];
        const int c0 = 1 + s * SEG;
        float pref[SEG];
        float run = 0.0f;
        #pragma unroll
        for (int k = 0; k < SEG; ++k) { run += row[c0 + k]; pref[k] = run; }
        const float v0 = __shfl(run, bl, 64), v1 = __shfl(run, bl + 1, 64),
                    v2 = __shfl(run, bl + 2, 64);
        float off = 0.0f;
        if (s > 0) off += v0;
        if (s > 1) off += v1;
        if (s > 2) off += v2;
        #pragma unroll
        for (int k = 0; k < SEG; ++k) row[c0 + k] = pref[k] + off;
    }
}

__device__ __forceinline__ void colscan_t(float* __restrict__ S, int t0, int nt,
                                          int lane) {
    const int bl = lane & ~3;
    for (int t = t0; t < HW * 4; t += nt) {
        const int c = t >> 2, s = t & 3;
        float* col = &S[c + 1];
        const int r0 = 1 + s * SEG;
        float pref[SEG];
        float run = 0.0f;
        #pragma unroll
        for (int k = 0; k < SEG; ++k) { run += col[(r0 + k) * PITCH]; pref[k] = run; }
        const float v0 = __shfl(run, bl, 64), v1 = __shfl(run, bl + 1, 64),
                    v2 = __shfl(run, bl + 2, 64);
        float off = 0.0f;
        if (s > 0) off += v0;
        if (s > 1) off += v1;
        if (s > 2) off += v2;
        #pragma unroll
        for (int k = 0; k < SEG; ++k) col[(r0 + k) * PITCH] = pref[k] + off;
    }
}

__global__ __launch_bounds__(BLOCK)
void window_crop_kernel(const float* __restrict__ x, float* __restrict__ out) {
    extern __shared__ float smem[];      // 2 * ISZ floats (102,152 B)
    __shared__ float wv[2][12];
    __shared__ int   wi[2][12];

    const int tid  = threadIdx.x;
    const int lane = tid & 63;
    const int b0   = blockIdx.x * IMGS;

    // zero border row 0 / col 0 of both buffers; init sync counter
    for (int i = tid; i < PITCH; i += BLOCK) {
        smem[i] = 0.0f;       smem[i * PITCH] = 0.0f;
        smem[ISZ + i] = 0.0f; smem[ISZ + i * PITCH] = 0.0f;
    }
    if (tid == 0) pctr = 0;

    // ---- prologue: image 0 -> buf0, scanned by the whole block ----
    load_img(x, b0, smem, tid, BLOCK);
    BAR();
    if (tid < HW * 4) rowscan_t(smem, tid, HW * 4, lane);
    BAR();
    if (tid < HW * 4) colscan_t(smem, tid, HW * 4, lane);
    BAR();

    // ---- steady state: windows(n) crew || prep(n+1) crew ----
    int tgt = 0;
    for (int n = 0; n < IMGS; ++n) {
        const int par = n & 1;
        if (tid < WCREW) {
            // finish image n-1's argmax (parity slot par^1: no writer until n+1)
            if (tid == 0 && n > 0) {
                float bv = wv[par ^ 1][0]; int bi = wi[par ^ 1][0];
                #pragma unroll
                for (int k = 1; k < 12; ++k)
                    if (wv[par ^ 1][k] > bv ||
                        (wv[par ^ 1][k] == bv && wi[par ^ 1][k] < bi)) {
                        bv = wv[par ^ 1][k]; bi = wi[par ^ 1][k];
                    }
                out[b0 + n - 1]           = (float)bi;
                out[B_TOTAL + b0 + n - 1] = bv;
            }
            const float* Sn = smem + par * ISZ;
            float* gout = out + 2 * B_TOTAL + (size_t)(b0 + n) * TOTAL_W;
            float bestv = -3.402823466e+38f;
            int   besti = 0;
            windows_group<32, 32,     0, true >(Sn, gout, tid, bestv, besti);
            windows_group<25, 39,  6561, true >(Sn, gout, tid, bestv, besti);
            windows_group<39, 25, 13073, true >(Sn, gout, tid, bestv, besti);
            windows_group<38, 26, 19585, true >(Sn, gout, tid, bestv, besti);
            windows_group<26, 38, 26110, false>(Sn, gout, tid, bestv, besti);
            #pragma unroll
            for (int d = 32; d > 0; d >>= 1) {
                const float ov = __shfl_down(bestv, d, 64);
                const int   oi = __shfl_down(besti, d, 64);
                if (ov > bestv || (ov == bestv && oi < besti)) { bestv = ov; besti = oi; }
            }
            if (lane == 0) { wv[par][tid >> 6] = bestv; wi[par][tid >> 6] = besti; }
        } else if (n + 1 < IMGS) {
            const int pt = tid - WCREW;              // 0..255
            float* Sx = smem + ((n + 1) & 1) * ISZ;  // freed at end of iter n-1
            load_img(x, b0 + n + 1, Sx, pt, PCREW);
            tgt += 4; psync(lane, tgt);              // loads in LDS
            rowscan_t(Sx, pt, PCREW, lane);
            tgt += 4; psync(lane, tgt);              // rows done
            colscan_t(Sx, pt, PCREW, lane);
        }
        BAR();                                       // buffer handoff
    }

    // final image's argmax
    if (tid == 0) {
        const int par = (IMGS - 1) & 1;
        float bv = wv[par][0]; int bi = wi[par][0];
        #pragma unroll
        for (int k = 1; k < 12; ++k)
            if (wv[par][k] > bv || (wv[par][k] == bv && wi[par][k] < bi)) {
                bv = wv[par][k]; bi = wi[par][k];
            }
        out[b0 + IMGS - 1]           = (float)bi;
        out[B_TOTAL + b0 + IMGS - 1] = bv;
    }
}

extern "C" void kernel_launch(void* const* d_in, const int* in_sizes, int n_in,
                              void* d_out, int out_size, void* d_ws, size_t ws_size,
                              hipStream_t stream) {
    const float* x = (const float*)d_in[0];
    float* out     = (float*)d_out;
    window_crop_kernel<<<GRID, BLOCK, 2 * ISZ * sizeof(float), stream>>>(x, out);
}